// Round 6
// baseline (165.806 us; speedup 1.0000x reference)
//
#include <hip/hip_runtime.h>
#include <math.h>

#define NB     512
#define NV     6890
#define NF     13776
#define NVHD   20000
#define NPARTS 10
#define NTHREADS 1024
#define NWAVES (NTHREADS/64)
#define CUT    6698   // verts >= CUT (192 of them) read from global (L2-hot)
#define NCH    ((NVHD + 63) / 64)   // 313 radix chunks of one wave each

// ---- Precompute batch-independent packed gather tables ----
__global__ void build_tables(const float* __restrict__ bary,
                             const int*   __restrict__ faces,
                             const int*   __restrict__ hd_fid,
                             const int*   __restrict__ part_fid,
                             uint2* __restrict__ f_pack,    // [NF]  {i0|i1<<16, i2|p<<16}
                             uint4* __restrict__ hd_pack,   // [NVHD]{i0|i1<<16, i2|p<<16, w0, w1}
                             unsigned* __restrict__ hd_key) // [NVHD] fid (radix key)
{
    int i = blockIdx.x * blockDim.x + threadIdx.x;
    if (i < NF) {
        unsigned a = (unsigned)faces[3*i+0] | ((unsigned)faces[3*i+1] << 16);
        unsigned b = (unsigned)faces[3*i+2] | ((unsigned)part_fid[i]  << 16);
        f_pack[i] = make_uint2(a, b);
    }
    if (i < NVHD) {
        int fid = hd_fid[i];
        unsigned a = (unsigned)faces[3*fid+0] | ((unsigned)faces[3*fid+1] << 16);
        unsigned b = (unsigned)faces[3*fid+2] | ((unsigned)part_fid[fid]  << 16);
        float b0 = bary[3*i+0], b1 = bary[3*i+1], b2 = bary[3*i+2];
        float inv = 1.0f / (b0 + b1 + b2);
        hd_pack[i] = make_uint4(a, b, __float_as_uint(b0*inv), __float_as_uint(b1*inv));
        hd_key[i]  = (unsigned)fid;
    }
}

// ---- Deterministic stable LSD radix pass (5-bit digit), single block ----
// Wave-chunk stable ranks via ballot match-any; no atomics -> bit-deterministic.
__global__ __launch_bounds__(1024) void radix_pass(
    const uint4*    __restrict__ in_pack,
    const unsigned* __restrict__ in_key,
    uint4*          __restrict__ out_pack,
    unsigned*       __restrict__ out_key,
    int shift)
{
    __shared__ unsigned hist[32][NCH];
    __shared__ unsigned tot[32];
    __shared__ unsigned base[32];
    const int tid = threadIdx.x, wave = tid >> 6, lane = tid & 63;
    const unsigned long long lowmask = (1ull << lane) - 1ull;

    for (int k = tid; k < 32 * NCH; k += 1024) (&hist[0][0])[k] = 0u;
    __syncthreads();

    // phase 1: per-chunk per-digit counts (leader lane writes popcount)
    for (int c = wave; c < NCH; c += NWAVES) {
        int i = c * 64 + lane;
        bool valid = i < NVHD;
        unsigned d = valid ? ((in_key[i] >> shift) & 31u) : 0u;
        unsigned long long m = ~0ull;
        #pragma unroll
        for (int b = 0; b < 5; b++) {
            unsigned long long bb = __ballot(valid && ((d >> b) & 1u));
            m &= ((d >> b) & 1u) ? bb : ~bb;
        }
        m &= __ballot(valid);
        if (valid && (m & lowmask) == 0ull)
            hist[d][c] = (unsigned)__popcll(m);
    }
    __syncthreads();

    // phase 2: exclusive scan per digit row (wave-parallel; wave w owns rows w, w+16)
    for (int r = wave; r < 32; r += NWAVES) {
        unsigned carry = 0;
        #pragma unroll
        for (int seg = 0; seg < (NCH + 63) / 64; seg++) {
            int idx = seg * 64 + lane;
            unsigned v = (idx < NCH) ? hist[r][idx] : 0u;
            unsigned incl = v;
            #pragma unroll
            for (int off = 1; off < 64; off <<= 1) {
                unsigned n = __shfl_up(incl, off, 64);
                if (lane >= off) incl += n;
            }
            if (idx < NCH) hist[r][idx] = incl - v + carry;
            carry += __shfl(incl, 63, 64);
        }
        if (lane == 0) tot[r] = carry;
    }
    __syncthreads();
    if (tid == 0) {
        unsigned r = 0;
        #pragma unroll
        for (int d = 0; d < 32; d++) { base[d] = r; r += tot[d]; }
    }
    __syncthreads();

    // phase 3: stable scatter
    for (int c = wave; c < NCH; c += NWAVES) {
        int i = c * 64 + lane;
        bool valid = i < NVHD;
        unsigned key = valid ? in_key[i] : 0u;
        unsigned d = (key >> shift) & 31u;
        unsigned long long m = ~0ull;
        #pragma unroll
        for (int b = 0; b < 5; b++) {
            unsigned long long bb = __ballot(valid && ((d >> b) & 1u));
            m &= ((d >> b) & 1u) ? bb : ~bb;
        }
        m &= __ballot(valid);
        if (valid) {
            unsigned rank = (unsigned)__popcll(m & lowmask);
            unsigned pos = base[d] + hist[d][c] + rank;
            out_key[pos]  = key;
            out_pack[pos] = in_pack[i];
        }
    }
}

__global__ __launch_bounds__(NTHREADS, 8) void stab_kernel(
    const float* __restrict__ vertices,   // [B][V][3] f32
    const uint2* __restrict__ f_pack,     // [NF]
    const uint4* __restrict__ hd_pack,    // [NVHD] sorted by fid
    float*       __restrict__ out)        // [B]
{
    __shared__ float2 sxy[CUT];
    __shared__ float  szz[CUT];
    __shared__ float  spart[NPARTS];
    __shared__ float  sredp[NWAVES][NPARTS];

    const int tid  = threadIdx.x;
    const int b    = blockIdx.x;
    const int wave = tid >> 6;
    const int lane = tid & 63;
    const float* __restrict__ vb = vertices + (size_t)b * (NV * 3);

    for (int v = tid; v < CUT; v += NTHREADS) {
        float x = vb[3 * v + 0];
        float y = vb[3 * v + 1];
        float z = vb[3 * v + 2];
        sxy[v] = make_float2(x, y);
        szz[v] = z;
    }
    __syncthreads();

#define GETV(idx, X, Y, Z) do {                                   \
        int _ic = (idx) < CUT ? (idx) : CUT - 1;                  \
        float2 _t = sxy[_ic]; float _z = szz[_ic];                \
        X = _t.x; Y = _t.y; Z = _z;                               \
        if ((idx) >= CUT) {                                       \
            X = vb[3*(idx)+0]; Y = vb[3*(idx)+1]; Z = vb[3*(idx)+2]; \
        }                                                         \
    } while (0)

    // ---- Phase B: per-face signed volumes -> per-part sums ----
    float accp[NPARTS];
    #pragma unroll
    for (int q = 0; q < NPARTS; q++) accp[q] = 0.f;

    #pragma unroll 4
    for (int f = tid; f < NF; f += NTHREADS) {
        uint2 ft = f_pack[f];
        int i0 = ft.x & 0xFFFF, i1 = ft.x >> 16;
        int i2 = ft.y & 0xFFFF, p  = ft.y >> 16;
        float x0, y0, z0, x1, y1, z1, x2, y2, z2;
        GETV(i0, x0, y0, z0);
        GETV(i1, x1, y1, z1);
        GETV(i2, x2, y2, z2);
        float cx = y0 * z1 - z0 * y1;
        float cy = z0 * x1 - x0 * z1;
        float cz = x0 * y1 - y0 * x1;
        float vol = (cx * x2 + cy * y2 + cz * z2) * (1.0f / 6.0f);
        #pragma unroll
        for (int q = 0; q < NPARTS; q++) accp[q] += (p == q) ? vol : 0.f;
    }
    #pragma unroll
    for (int q = 0; q < NPARTS; q++) {
        float s = accp[q];
        #pragma unroll
        for (int off = 32; off > 0; off >>= 1) s += __shfl_down(s, off, 64);
        accp[q] = s;
    }
    if (lane == 0) {
        #pragma unroll
        for (int q = 0; q < NPARTS; q++) sredp[wave][q] = accp[q];
    }
    __syncthreads();
    if (tid < NPARTS) {
        float s = 0.f;
        #pragma unroll
        for (int w = 0; w < NWAVES; w++) s += sredp[w][tid];
        spart[tid] = s;
    }
    __syncthreads();

    // ---- Phase C: HD vertices (fid-sorted -> LDS broadcast dedup) ----
    float sVx = 0.f, sVy = 0.f, sVz = 0.f, sVol = 0.f;
    float sPx = 0.f, sPy = 0.f, sPz = 0.f, sPw  = 0.f;

    #pragma unroll 4
    for (int v = tid; v < NVHD; v += NTHREADS) {
        uint4 hp = hd_pack[v];
        int i0 = hp.x & 0xFFFF, i1 = hp.x >> 16;
        int i2 = hp.y & 0xFFFF, p  = hp.y >> 16;
        float w0 = __uint_as_float(hp.z);
        float w1 = __uint_as_float(hp.w);
        float w2 = 1.0f - w0 - w1;
        float x0, y0, z0, x1, y1, z1, x2, y2, z2;
        GETV(i0, x0, y0, z0);
        GETV(i1, x1, y1, z1);
        GETV(i2, x2, y2, z2);
        float x = w0 * x0 + w1 * x1 + w2 * x2;
        float y = w0 * y0 + w1 * y1 + w2 * y2;
        float z = w0 * z0 + w1 * z1 + w2 * z2;
        float vol = spart[p];
        float pw  = (y < 0.f) ? fmaf(-100.f, y, 1.f) : __expf(-10.f * y);
        sVx += x * vol;  sVy += y * vol;  sVz += z * vol;  sVol += vol;
        sPx += x * pw;   sPy += y * pw;   sPz += z * pw;   sPw  += pw;
    }

    float vals[8] = {sVx, sVy, sVz, sVol, sPx, sPy, sPz, sPw};
    #pragma unroll
    for (int q = 0; q < 8; q++) {
        float s = vals[q];
        #pragma unroll
        for (int off = 32; off > 0; off >>= 1) s += __shfl_down(s, off, 64);
        vals[q] = s;
    }
    float* sred8 = &sredp[0][0];
    if (lane == 0) {
        #pragma unroll
        for (int q = 0; q < 8; q++) sred8[wave * 8 + q] = vals[q];
    }
    __syncthreads();
    if (tid == 0) {
        float r[8];
        #pragma unroll
        for (int q = 0; q < 8; q++) {
            float s = 0.f;
            #pragma unroll
            for (int w = 0; w < NWAVES; w++) s += sred8[w * 8 + q];
            r[q] = s;
        }
        float invVol = 1.0f / r[3];
        float invPw  = 1.0f / (r[7] + 1e-6f);
        float comx = r[0] * invVol, comz = r[2] * invVol;
        float copx = r[4] * invPw,  copz = r[6] * invPw;
        float d0 = comx - copx, d2 = comz - copz;
        out[b] = sqrtf(d0 * d0 + d2 * d2);
    }
#undef GETV
}

extern "C" void kernel_launch(void* const* d_in, const int* in_sizes, int n_in,
                              void* d_out, int out_size, void* d_ws, size_t ws_size,
                              hipStream_t stream) {
    const float* vertices = (const float*)d_in[0];
    const float* bary     = (const float*)d_in[1];
    const int*   faces    = (const int*)d_in[2];
    const int*   hd_fid   = (const int*)d_in[3];
    const int*   part_fid = (const int*)d_in[4];
    float* out = (float*)d_out;

    // ws layout (16B-aligned chunks)
    char* ws = (char*)d_ws;
    uint2*    f_pack = (uint2*)ws;                       size_t off = (size_t)NF * 8;      // 110208
    uint4*    packA  = (uint4*)(ws + off);               off += (size_t)NVHD * 16;         // 320000
    uint4*    packB  = (uint4*)(ws + off);               off += (size_t)NVHD * 16;
    unsigned* keyA   = (unsigned*)(ws + off);            off += (size_t)NVHD * 4;
    unsigned* keyB   = (unsigned*)(ws + off);            off += (size_t)NVHD * 4;

    build_tables<<<(NVHD + 255) / 256, 256, 0, stream>>>(bary, faces, hd_fid, part_fid,
                                                         f_pack, packA, keyA);
    // 3 stable 5-bit passes: fid < 13776 < 2^15
    radix_pass<<<1, 1024, 0, stream>>>(packA, keyA, packB, keyB, 0);
    radix_pass<<<1, 1024, 0, stream>>>(packB, keyB, packA, keyA, 5);
    radix_pass<<<1, 1024, 0, stream>>>(packA, keyA, packB, keyB, 10);

    stab_kernel<<<NB, NTHREADS, 0, stream>>>(vertices, f_pack, packB, out);
}

// Round 7
// 145.379 us; speedup vs baseline: 1.1405x; 1.1405x over previous
//
#include <hip/hip_runtime.h>
#include <math.h>

#define NB     512
#define NV     6890
#define NF     13776
#define NVHD   20000
#define NPARTS 10
#define NTHREADS 1024
#define NWAVES (NTHREADS/64)
#define CAP    6768             // LDS vertex slots; 12*CAP + 680 = 81896 <= 81920 (2 blocks/CU)
#define NEVICT (NV - CAP)       // 122 least-referenced vertices read from global

// ---- K0: zero the ref-count buffer ----
__global__ void zero_cnt(int* __restrict__ cnt) {
    int i = blockIdx.x * blockDim.x + threadIdx.x;
    if (i < NV) cnt[i] = 0;
}

// ---- K1: build packed tables (original indices) + reference counts ----
__global__ void build_tables(const float* __restrict__ bary,
                             const int*   __restrict__ faces,
                             const int*   __restrict__ hd_fid,
                             const int*   __restrict__ part_fid,
                             uint2* __restrict__ f_pack,    // [NF]  {i0|i1<<16, i2|p<<16}
                             uint4* __restrict__ hd_pack,   // [NVHD]{i0|i1<<16, i2|p<<16, w0, w1}
                             int*   __restrict__ cnt)       // [NV] gather refs
{
    int i = blockIdx.x * blockDim.x + threadIdx.x;
    if (i < NF) {
        int i0 = faces[3*i+0], i1 = faces[3*i+1], i2 = faces[3*i+2];
        f_pack[i] = make_uint2((unsigned)i0 | ((unsigned)i1 << 16),
                               (unsigned)i2 | ((unsigned)part_fid[i] << 16));
        atomicAdd(&cnt[i0], 1); atomicAdd(&cnt[i1], 1); atomicAdd(&cnt[i2], 1);
    }
    if (i < NVHD) {
        int fid = hd_fid[i];
        int i0 = faces[3*fid+0], i1 = faces[3*fid+1], i2 = faces[3*fid+2];
        float b0 = bary[3*i+0], b1 = bary[3*i+1], b2 = bary[3*i+2];
        float inv = 1.0f / (b0 + b1 + b2);
        hd_pack[i] = make_uint4((unsigned)i0 | ((unsigned)i1 << 16),
                                (unsigned)i2 | ((unsigned)part_fid[fid] << 16),
                                __float_as_uint(b0*inv), __float_as_uint(b1*inv));
        atomicAdd(&cnt[i0], 1); atomicAdd(&cnt[i1], 1); atomicAdd(&cnt[i2], 1);
    }
}

// ---- K2: one-wave exact selection of NEVICT least-referenced vertices ----
// Deterministic: integer hist + scans; ties broken by vertex id.
__global__ __launch_bounds__(64) void select_perm(
    const int* __restrict__ cnt,
    int* __restrict__ newid,       // [NV] orig -> slot
    int* __restrict__ old_of_new)  // [NV] slot -> orig
{
    __shared__ int hist[64 * 64];  // lane-striped [lane][bin]
    __shared__ int tr[2];
    const int lane = threadIdx.x;
    const int per  = (NV + 63) / 64;            // 108
    const int beg  = lane * per;
    const int end  = (beg + per < NV) ? beg + per : NV;

    for (int b = 0; b < 64; b++) hist[lane * 64 + b] = 0;
    __syncthreads();
    for (int v = beg; v < end; v++) {
        int c = cnt[v]; c = c > 63 ? 63 : c;
        hist[lane * 64 + c]++;
    }
    __syncthreads();
    // lane b owns bin b: total over stripes
    int tot = 0;
    for (int l = 0; l < 64; l++) tot += hist[l * 64 + lane];
    // exclusive scan over bins (lane order = count order)
    int incl = tot;
    for (int off = 1; off < 64; off <<= 1) { int n = __shfl_up(incl, off, 64); if (lane >= off) incl += n; }
    int under = incl - tot;                     // #{cnt < lane}
    if (under <= NEVICT && NEVICT < under + tot) { tr[0] = lane; tr[1] = NEVICT - under; }
    __syncthreads();
    const int t = tr[0], r = tr[1];             // evict all cnt<t, plus first r (by id) of cnt==t

    // per-lane-block counts of a=(cnt>t), e=(cnt==t)
    int a = 0, e = 0;
    for (int v = beg; v < end; v++) {
        int c = cnt[v]; c = c > 63 ? 63 : c;
        a += (c > t); e += (c == t);
    }
    int A = a; for (int off = 1; off < 64; off <<= 1) { int n = __shfl_up(A, off, 64); if (lane >= off) A += n; } A -= a;
    int E = e; for (int off = 1; off < 64; off <<= 1) { int n = __shfl_up(E, off, 64); if (lane >= off) E += n; } E -= e;

    int a_run = A, e_run = E;
    for (int v = beg; v < end; v++) {
        int c = cnt[v]; c = c > 63 ? 63 : c;
        int eq_kept_before = e_run - r > 0 ? e_run - r : 0;
        int kb = a_run + eq_kept_before;        // kept before v (global id order)
        bool kept = (c > t) || (c == t && e_run >= r);
        int slot = kept ? kb : (CAP + (v - kb));
        newid[v] = slot;
        old_of_new[slot] = v;
        if (c > t) a_run++; else if (c == t) e_run++;
    }
}

// ---- K3: rewrite table indices through the permutation ----
__global__ void rewrite_tables(uint2* __restrict__ f_pack,
                               uint4* __restrict__ hd_pack,
                               const int* __restrict__ newid)
{
    int i = blockIdx.x * blockDim.x + threadIdx.x;
    if (i < NF) {
        uint2 ft = f_pack[i];
        unsigned i0 = newid[ft.x & 0xFFFF], i1 = newid[ft.x >> 16];
        unsigned i2 = newid[ft.y & 0xFFFF], p  = ft.y >> 16;
        f_pack[i] = make_uint2(i0 | (i1 << 16), i2 | (p << 16));
    }
    if (i < NVHD) {
        uint4 hp = hd_pack[i];
        unsigned i0 = newid[hp.x & 0xFFFF], i1 = newid[hp.x >> 16];
        unsigned i2 = newid[hp.y & 0xFFFF], p  = hp.y >> 16;
        hd_pack[i] = make_uint4(i0 | (i1 << 16), i2 | (p << 16), hp.z, hp.w);
    }
}

__global__ __launch_bounds__(NTHREADS, 8) void stab_kernel(
    const float* __restrict__ vertices,    // [B][V][3] f32
    const uint2* __restrict__ f_pack,      // [NF] slot indices
    const uint4* __restrict__ hd_pack,     // [NVHD] slot indices
    const int*   __restrict__ newid,       // [NV]
    const int*   __restrict__ old_of_new,  // [NV]
    float*       __restrict__ out)         // [B]
{
    __shared__ float2 sxy[CAP];            // 54144 B
    __shared__ float  szz[CAP];            // 27072 B
    __shared__ float  spart[NPARTS];       // 40 B
    __shared__ float  sredp[NWAVES][NPARTS]; // 640 B   (total 81896 <= 81920)

    const int tid  = threadIdx.x;
    const int b    = blockIdx.x;
    const int wave = tid >> 6;
    const int lane = tid & 63;
    const float* __restrict__ vb = vertices + (size_t)b * (NV * 3);

    // ---- Phase A: coalesced read in id order, scatter to LDS by slot ----
    for (int v = tid; v < NV; v += NTHREADS) {
        float x = vb[3 * v + 0];
        float y = vb[3 * v + 1];
        float z = vb[3 * v + 2];
        int s = newid[v];
        if (s < CAP) { sxy[s] = make_float2(x, y); szz[s] = z; }
    }
    __syncthreads();

    // gather: LDS for slot<CAP; rare global fallback (evicted = least-referenced)
#define GETV(idx, X, Y, Z) do {                                     \
        int _s = (idx); int _c = _s < CAP ? _s : 0;                 \
        float2 _t = sxy[_c]; float _z = szz[_c];                    \
        X = _t.x; Y = _t.y; Z = _z;                                 \
        if (_s >= CAP) {                                            \
            int _o = old_of_new[_s];                                \
            X = vb[3*_o+0]; Y = vb[3*_o+1]; Z = vb[3*_o+2];         \
        }                                                           \
    } while (0)

    // ---- Phase B: per-face signed volumes -> per-part sums ----
    float accp[NPARTS];
    #pragma unroll
    for (int q = 0; q < NPARTS; q++) accp[q] = 0.f;

    #pragma unroll 4
    for (int f = tid; f < NF; f += NTHREADS) {
        uint2 ft = f_pack[f];
        int i0 = ft.x & 0xFFFF, i1 = ft.x >> 16;
        int i2 = ft.y & 0xFFFF, p  = ft.y >> 16;
        float x0, y0, z0, x1, y1, z1, x2, y2, z2;
        GETV(i0, x0, y0, z0);
        GETV(i1, x1, y1, z1);
        GETV(i2, x2, y2, z2);
        float cx = y0 * z1 - z0 * y1;
        float cy = z0 * x1 - x0 * z1;
        float cz = x0 * y1 - y0 * x1;
        float vol = (cx * x2 + cy * y2 + cz * z2) * (1.0f / 6.0f);
        #pragma unroll
        for (int q = 0; q < NPARTS; q++) accp[q] += (p == q) ? vol : 0.f;
    }
    #pragma unroll
    for (int q = 0; q < NPARTS; q++) {
        float s = accp[q];
        #pragma unroll
        for (int off = 32; off > 0; off >>= 1) s += __shfl_down(s, off, 64);
        accp[q] = s;
    }
    if (lane == 0) {
        #pragma unroll
        for (int q = 0; q < NPARTS; q++) sredp[wave][q] = accp[q];
    }
    __syncthreads();
    if (tid < NPARTS) {
        float s = 0.f;
        #pragma unroll
        for (int w = 0; w < NWAVES; w++) s += sredp[w][tid];
        spart[tid] = s;
    }
    __syncthreads();

    // ---- Phase C: HD vertices, COM / CoP accumulators ----
    float sVx = 0.f, sVy = 0.f, sVz = 0.f, sVol = 0.f;
    float sPx = 0.f, sPy = 0.f, sPz = 0.f, sPw  = 0.f;

    #pragma unroll 4
    for (int v = tid; v < NVHD; v += NTHREADS) {
        uint4 hp = hd_pack[v];
        int i0 = hp.x & 0xFFFF, i1 = hp.x >> 16;
        int i2 = hp.y & 0xFFFF, p  = hp.y >> 16;
        float w0 = __uint_as_float(hp.z);
        float w1 = __uint_as_float(hp.w);
        float w2 = 1.0f - w0 - w1;
        float x0, y0, z0, x1, y1, z1, x2, y2, z2;
        GETV(i0, x0, y0, z0);
        GETV(i1, x1, y1, z1);
        GETV(i2, x2, y2, z2);
        float x = w0 * x0 + w1 * x1 + w2 * x2;
        float y = w0 * y0 + w1 * y1 + w2 * y2;
        float z = w0 * z0 + w1 * z1 + w2 * z2;
        float vol = spart[p];
        float pw  = (y < 0.f) ? fmaf(-100.f, y, 1.f) : __expf(-10.f * y);
        sVx += x * vol;  sVy += y * vol;  sVz += z * vol;  sVol += vol;
        sPx += x * pw;   sPy += y * pw;   sPz += z * pw;   sPw  += pw;
    }

    float vals[8] = {sVx, sVy, sVz, sVol, sPx, sPy, sPz, sPw};
    #pragma unroll
    for (int q = 0; q < 8; q++) {
        float s = vals[q];
        #pragma unroll
        for (int off = 32; off > 0; off >>= 1) s += __shfl_down(s, off, 64);
        vals[q] = s;
    }
    float* sred8 = &sredp[0][0];   // reuse (dead after spart), 512 B <= 640 B
    if (lane == 0) {
        #pragma unroll
        for (int q = 0; q < 8; q++) sred8[wave * 8 + q] = vals[q];
    }
    __syncthreads();
    if (tid == 0) {
        float r[8];
        #pragma unroll
        for (int q = 0; q < 8; q++) {
            float s = 0.f;
            #pragma unroll
            for (int w = 0; w < NWAVES; w++) s += sred8[w * 8 + q];
            r[q] = s;
        }
        float invVol = 1.0f / r[3];
        float invPw  = 1.0f / (r[7] + 1e-6f);
        float comx = r[0] * invVol, comz = r[2] * invVol;
        float copx = r[4] * invPw,  copz = r[6] * invPw;
        float d0 = comx - copx, d2 = comz - copz;
        out[b] = sqrtf(d0 * d0 + d2 * d2);
    }
#undef GETV
}

extern "C" void kernel_launch(void* const* d_in, const int* in_sizes, int n_in,
                              void* d_out, int out_size, void* d_ws, size_t ws_size,
                              hipStream_t stream) {
    const float* vertices = (const float*)d_in[0];
    const float* bary     = (const float*)d_in[1];
    const int*   faces    = (const int*)d_in[2];
    const int*   hd_fid   = (const int*)d_in[3];
    const int*   part_fid = (const int*)d_in[4];
    float* out = (float*)d_out;

    // ws layout (16B-aligned chunks)
    char* ws = (char*)d_ws;
    uint2* f_pack      = (uint2*)ws;              size_t off = (size_t)NF * 8;    // 110208
    uint4* hd_pack     = (uint4*)(ws + off);      off += (size_t)NVHD * 16;       // 320000
    int*   cnt         = (int*)(ws + off);        off += (size_t)NV * 4;          // 27560
    int*   newid       = (int*)(ws + off);        off += (size_t)NV * 4;
    int*   old_of_new  = (int*)(ws + off);        off += (size_t)NV * 4;

    zero_cnt<<<(NV + 1023) / 1024, 1024, 0, stream>>>(cnt);
    build_tables<<<(NVHD + 255) / 256, 256, 0, stream>>>(bary, faces, hd_fid, part_fid,
                                                         f_pack, hd_pack, cnt);
    select_perm<<<1, 64, 0, stream>>>(cnt, newid, old_of_new);
    rewrite_tables<<<(NVHD + 255) / 256, 256, 0, stream>>>(f_pack, hd_pack, newid);

    stab_kernel<<<NB, NTHREADS, 0, stream>>>(vertices, f_pack, hd_pack, newid, old_of_new, out);
}

// Round 8
// 64.557 us; speedup vs baseline: 2.5684x; 2.2520x over previous
//
#include <hip/hip_runtime.h>
#include <math.h>

#define NB       512
#define NV       6890
#define NF       13776
#define NVHD     20000
#define NPARTS   10
#define NT       1024
#define NWAVES   (NT/64)
#define ITB      14                 // ceil(NF/NT)
#define ITC      20                 // ceil(NVHD/NT)
#define NF_PAD   (ITB*NT)           // 14336
#define NVHD_PAD (ITC*NT)           // 20480
#define TAILC    (NVHD - (ITC-1)*NT) // 544

// ---- Precompute: packed, PADDED gather tables (batch-independent) ----
__global__ void build_tables(const float* __restrict__ bary,
                             const int*   __restrict__ faces,
                             const int*   __restrict__ hd_fid,
                             const int*   __restrict__ part_fid,
                             uint2* __restrict__ f_pack,    // [NF_PAD]
                             uint4* __restrict__ hd_pack)   // [NVHD_PAD]
{
    int i = blockIdx.x * blockDim.x + threadIdx.x;
    if (i < NF_PAD) {
        if (i < NF) {
            f_pack[i] = make_uint2((unsigned)faces[3*i+0] | ((unsigned)faces[3*i+1] << 16),
                                   (unsigned)faces[3*i+2] | ((unsigned)part_fid[i]  << 16));
        } else {
            f_pack[i] = make_uint2(0u, 0u);   // identical verts -> vol = 0 (safe)
        }
    }
    if (i < NVHD_PAD) {
        if (i < NVHD) {
            int fid = hd_fid[i];
            float b0 = bary[3*i+0], b1 = bary[3*i+1], b2 = bary[3*i+2];
            float inv = 1.0f / (b0 + b1 + b2);
            hd_pack[i] = make_uint4((unsigned)faces[3*fid+0] | ((unsigned)faces[3*fid+1] << 16),
                                    (unsigned)faces[3*fid+2] | ((unsigned)part_fid[fid] << 16),
                                    __float_as_uint(b0*inv), __float_as_uint(b1*inv));
        } else {
            hd_pack[i] = make_uint4(0u, 0u, 0u, 0u); // masked at tail iteration
        }
    }
}

__global__ __launch_bounds__(NT, 4) void stab_kernel(
    const float* __restrict__ vertices,   // [B][V][3] f32
    const uint2* __restrict__ f_pack,     // [NF_PAD]
    const uint4* __restrict__ hd_pack,    // [NVHD_PAD]
    float*       __restrict__ out)        // [B]
{
    __shared__ float4 sv[NV];               // 110240 B (1 block/CU)
    __shared__ float  spart[NPARTS];
    __shared__ float  sredp[NWAVES][NPARTS];

    const int tid  = threadIdx.x;
    const int b    = blockIdx.x;
    const int wave = tid >> 6;
    const int lane = tid & 63;
    const float* __restrict__ vb = vertices + (size_t)b * (NV * 3);

    // ---- Phase A: stage vertices into LDS (float4 -> single b128 gathers) ----
    for (int v = tid; v < NV; v += NT)
        sv[v] = make_float4(vb[3*v+0], vb[3*v+1], vb[3*v+2], 0.f);
    __syncthreads();

    // ---- Phase B: 3-stage software pipeline (T(it+2) | G(it+1) | C(it)) ----
    float accp[NPARTS];
    #pragma unroll
    for (int q = 0; q < NPARTS; q++) accp[q] = 0.f;

    {
        uint2  ftb[2];
        float4 a0[2], a1[2], a2[2];
        int    pb[2];

        ftb[0] = f_pack[tid];
        {
            int i0 = ftb[0].x & 0xFFFF, i1 = ftb[0].x >> 16, i2 = ftb[0].y & 0xFFFF;
            pb[0] = (int)(ftb[0].y >> 16);
            a0[0] = sv[i0]; a1[0] = sv[i1]; a2[0] = sv[i2];
        }
        ftb[1] = f_pack[tid + NT];

        #pragma unroll
        for (int it = 0; it < ITB; ++it) {
            const int cur = it & 1, nxt = cur ^ 1;
            if (it + 2 < ITB) ftb[cur] = f_pack[tid + (it + 2) * NT];
            if (it + 1 < ITB) {
                int i0 = ftb[nxt].x & 0xFFFF, i1 = ftb[nxt].x >> 16, i2 = ftb[nxt].y & 0xFFFF;
                pb[nxt] = (int)(ftb[nxt].y >> 16);
                a0[nxt] = sv[i0]; a1[nxt] = sv[i1]; a2[nxt] = sv[i2];
            }
            float4 t0 = a0[cur], t1 = a1[cur], t2 = a2[cur];
            float cx = t0.y * t1.z - t0.z * t1.y;
            float cy = t0.z * t1.x - t0.x * t1.z;
            float cz = t0.x * t1.y - t0.y * t1.x;
            float vol = (cx * t2.x + cy * t2.y + cz * t2.z) * (1.0f / 6.0f);
            int p = pb[cur];
            #pragma unroll
            for (int q = 0; q < NPARTS; q++) accp[q] += (p == q) ? vol : 0.f;
        }
    }
    #pragma unroll
    for (int q = 0; q < NPARTS; q++) {
        float s = accp[q];
        #pragma unroll
        for (int off = 32; off > 0; off >>= 1) s += __shfl_down(s, off, 64);
        accp[q] = s;
    }
    if (lane == 0) {
        #pragma unroll
        for (int q = 0; q < NPARTS; q++) sredp[wave][q] = accp[q];
    }
    __syncthreads();
    if (tid < NPARTS) {
        float s = 0.f;
        #pragma unroll
        for (int w = 0; w < NWAVES; w++) s += sredp[w][tid];
        spart[tid] = s;
    }
    __syncthreads();

    // ---- Phase C: same pipeline over HD vertices ----
    float sVx = 0.f, sVy = 0.f, sVz = 0.f, sVol = 0.f;
    float sPx = 0.f, sPy = 0.f, sPz = 0.f, sPw  = 0.f;

    {
        uint4  ftc[2];
        float4 c0[2], c1[2], c2[2];
        float2 wgt[2];
        float  vv[2];

        ftc[0] = hd_pack[tid];
        {
            int i0 = ftc[0].x & 0xFFFF, i1 = ftc[0].x >> 16, i2 = ftc[0].y & 0xFFFF;
            int p  = (int)(ftc[0].y >> 16);
            wgt[0] = make_float2(__uint_as_float(ftc[0].z), __uint_as_float(ftc[0].w));
            c0[0] = sv[i0]; c1[0] = sv[i1]; c2[0] = sv[i2];
            vv[0] = spart[p];
        }
        ftc[1] = hd_pack[tid + NT];

        #pragma unroll
        for (int it = 0; it < ITC; ++it) {
            const int cur = it & 1, nxt = cur ^ 1;
            if (it + 2 < ITC) ftc[cur] = hd_pack[tid + (it + 2) * NT];
            if (it + 1 < ITC) {
                int i0 = ftc[nxt].x & 0xFFFF, i1 = ftc[nxt].x >> 16, i2 = ftc[nxt].y & 0xFFFF;
                int p  = (int)(ftc[nxt].y >> 16);
                wgt[nxt] = make_float2(__uint_as_float(ftc[nxt].z), __uint_as_float(ftc[nxt].w));
                c0[nxt] = sv[i0]; c1[nxt] = sv[i1]; c2[nxt] = sv[i2];
                vv[nxt] = spart[p];
            }
            float w0 = wgt[cur].x, w1 = wgt[cur].y;
            float w2 = 1.0f - w0 - w1;
            float4 t0 = c0[cur], t1 = c1[cur], t2 = c2[cur];
            float x = w0 * t0.x + w1 * t1.x + w2 * t2.x;
            float y = w0 * t0.y + w1 * t1.y + w2 * t2.y;
            float z = w0 * t0.z + w1 * t1.z + w2 * t2.z;
            float vol = vv[cur];
            float pw  = (y < 0.f) ? fmaf(-100.f, y, 1.f) : __expf(-10.f * y);
            if (it == ITC - 1) {                 // only tail iteration can be invalid
                float m = (tid < TAILC) ? 1.f : 0.f;
                vol *= m; pw *= m;
            }
            sVx += x * vol;  sVy += y * vol;  sVz += z * vol;  sVol += vol;
            sPx += x * pw;   sPy += y * pw;   sPz += z * pw;   sPw  += pw;
        }
    }

    float vals[8] = {sVx, sVy, sVz, sVol, sPx, sPy, sPz, sPw};
    #pragma unroll
    for (int q = 0; q < 8; q++) {
        float s = vals[q];
        #pragma unroll
        for (int off = 32; off > 0; off >>= 1) s += __shfl_down(s, off, 64);
        vals[q] = s;
    }
    float* sred8 = &sredp[0][0];   // reuse (dead after spart), 512 B <= 640 B
    if (lane == 0) {
        #pragma unroll
        for (int q = 0; q < 8; q++) sred8[wave * 8 + q] = vals[q];
    }
    __syncthreads();
    if (tid == 0) {
        float r[8];
        #pragma unroll
        for (int q = 0; q < 8; q++) {
            float s = 0.f;
            #pragma unroll
            for (int w = 0; w < NWAVES; w++) s += sred8[w * 8 + q];
            r[q] = s;
        }
        float invVol = 1.0f / r[3];
        float invPw  = 1.0f / (r[7] + 1e-6f);
        float comx = r[0] * invVol, comz = r[2] * invVol;
        float copx = r[4] * invPw,  copz = r[6] * invPw;
        float d0 = comx - copx, d2 = comz - copz;
        out[b] = sqrtf(d0 * d0 + d2 * d2);
    }
}

extern "C" void kernel_launch(void* const* d_in, const int* in_sizes, int n_in,
                              void* d_out, int out_size, void* d_ws, size_t ws_size,
                              hipStream_t stream) {
    const float* vertices = (const float*)d_in[0];
    const float* bary     = (const float*)d_in[1];
    const int*   faces    = (const int*)d_in[2];
    const int*   hd_fid   = (const int*)d_in[3];
    const int*   part_fid = (const int*)d_in[4];
    float* out = (float*)d_out;

    char* ws = (char*)d_ws;
    uint2* f_pack  = (uint2*)ws;                              // NF_PAD*8  = 114688
    uint4* hd_pack = (uint4*)(ws + (size_t)NF_PAD * 8);       // NVHD_PAD*16 = 327680

    build_tables<<<(NVHD_PAD + 255) / 256, 256, 0, stream>>>(bary, faces, hd_fid, part_fid,
                                                             f_pack, hd_pack);
    stab_kernel<<<NB, NT, 0, stream>>>(vertices, f_pack, hd_pack, out);
}